// Round 2
// baseline (3019.297 us; speedup 1.0000x reference)
//
#include <hip/hip_runtime.h>
#include <hip/hip_bf16.h>
#include <math.h>

// Problem constants
#define BH 16      // BATCH
#define LL 1024    // L = H*W
#define CC 256     // C
#define DD 512     // DIN
#define NST 16     // N (state dim)

typedef __attribute__((ext_vector_type(8))) short bf16x8;
typedef __attribute__((ext_vector_type(4))) float f32x4;

__device__ __forceinline__ float b2f(__hip_bfloat16 x) { return __bfloat162float(x); }
__device__ __forceinline__ __hip_bfloat16 f2b(float x) { return __float2bfloat16(x); }

// ---------------- block-wide sum over 256 threads (4 waves) ----------------
__device__ __forceinline__ float block_sum_256(float v, float* sb) {
  #pragma unroll
  for (int o = 32; o; o >>= 1) v += __shfl_xor(v, o);
  int w = threadIdx.x >> 6;
  __syncthreads();                       // protect previous use of sb
  if ((threadIdx.x & 63) == 0) sb[w] = v;
  __syncthreads();
  return sb[0] + sb[1] + sb[2] + sb[3];
}

// ---------------- f32 -> bf16 weight conversion ----------------
__global__ void k_cvtw(const float* __restrict__ in, __hip_bfloat16* __restrict__ out, long n) {
  long i = (long)blockIdx.x * blockDim.x + threadIdx.x;
  if (i < n) out[i] = f2b(in[i]);
}

// ---------------- layer0: LN(xt) || LN(hx) -> catn (bf16, B*L x 512) ----------------
__global__ __launch_bounds__(256) void k_ln_cat(const float* __restrict__ xt,
                                                const float* __restrict__ hx,
                                                const float* __restrict__ g,
                                                const float* __restrict__ bb,
                                                __hip_bfloat16* __restrict__ catn) {
  __shared__ float sb[4];
  long row = blockIdx.x;
  int tid = threadIdx.x;
  float xv = xt[row * CC + tid];
  float hv = hx[row * CC + tid];
  float mux = block_sum_256(xv, sb) * (1.f / CC);
  float muh = block_sum_256(hv, sb) * (1.f / CC);
  float dx = xv - mux, dh = hv - muh;
  float vx = block_sum_256(dx * dx, sb) * (1.f / CC);
  float vh = block_sum_256(dh * dh, sb) * (1.f / CC);
  float gg = g[tid], bbv = bb[tid];
  catn[row * 512 + tid]       = f2b(dx * rsqrtf(vx + 1e-5f) * gg + bbv);
  catn[row * 512 + 256 + tid] = f2b(dh * rsqrtf(vh + 1e-5f) * gg + bbv);
}

// ---------------- layer1: LN(xbuf) -> xn (bf16, B*L x 256) ----------------
__global__ __launch_bounds__(256) void k_ln(const float* __restrict__ xbuf,
                                            const float* __restrict__ g,
                                            const float* __restrict__ bb,
                                            __hip_bfloat16* __restrict__ xn) {
  __shared__ float sb[4];
  long row = blockIdx.x;
  int tid = threadIdx.x;
  float xv = xbuf[row * CC + tid];
  float mu = block_sum_256(xv, sb) * (1.f / CC);
  float d = xv - mu;
  float var = block_sum_256(d * d, sb) * (1.f / CC);
  xn[row * CC + tid] = f2b(d * rsqrtf(var + 1e-5f) * g[tid] + bb[tid]);
}

// ---------------- MFMA GEMM: out[r][c] = sum_k A[r][k]*W[c][k] (+epilogue) ----------------
// wave (64 thr) computes 64x64 tile; grid=(M/64, N/64). Wt is N x K (bf16).
// EPI 0: +bias(f32) -> outB (bf16, stride N)   (lin)
// EPI 1: col<512 -> outB[row*512+col]; else -> outB2[row*512+col-512]  (inproj split)
// EPI 2: -> outF (f32, stride N)               (xproj -> Dbl)
// EPI 3: + resid(f32) -> outF (f32, stride N)  (outproj + shortcut)
template <int EPI>
__global__ __launch_bounds__(64) void gemm_k(const __hip_bfloat16* __restrict__ A,
                                             const __hip_bfloat16* __restrict__ Wt,
                                             int K, int N,
                                             const float* __restrict__ bias,
                                             __hip_bfloat16* outB, __hip_bfloat16* outB2,
                                             float* outF, const float* resid) {
  int lane = threadIdx.x;
  int lr = lane & 15, lh = lane >> 4;
  long r0 = (long)blockIdx.x * 64;
  int c0 = blockIdx.y * 64;
  f32x4 acc[4][4] = {};
  for (int kk = 0; kk < K; kk += 32) {
    bf16x8 af[4], bf[4];
    #pragma unroll
    for (int mi = 0; mi < 4; mi++)
      af[mi] = *reinterpret_cast<const bf16x8*>(A + (r0 + mi * 16 + lr) * (long)K + kk + lh * 8);
    #pragma unroll
    for (int ci = 0; ci < 4; ci++)
      bf[ci] = *reinterpret_cast<const bf16x8*>(Wt + ((long)(c0 + ci * 16 + lr)) * (long)K + kk + lh * 8);
    #pragma unroll
    for (int mi = 0; mi < 4; mi++)
      #pragma unroll
      for (int ci = 0; ci < 4; ci++)
        acc[mi][ci] = __builtin_amdgcn_mfma_f32_16x16x32_bf16(af[mi], bf[ci], acc[mi][ci], 0, 0, 0);
  }
  #pragma unroll
  for (int mi = 0; mi < 4; mi++)
    #pragma unroll
    for (int ci = 0; ci < 4; ci++)
      #pragma unroll
      for (int r = 0; r < 4; r++) {
        long row = r0 + mi * 16 + lh * 4 + r;
        int col = c0 + ci * 16 + lr;
        float v = acc[mi][ci][r];
        if (EPI == 0) outB[row * (long)N + col] = f2b(v + bias[col]);
        if (EPI == 1) {
          if (col < 512) outB[row * 512 + col] = f2b(v);
          else           outB2[row * 512 + (col - 512)] = f2b(v);
        }
        if (EPI == 2) outF[row * (long)N + col] = v;
        if (EPI == 3) outF[row * (long)N + col] = v + resid[row * (long)N + col];
      }
}

// ---------------- depthwise 3x3 conv + bias + SiLU ----------------
__global__ void k_conv(const __hip_bfloat16* __restrict__ xcpre,
                       const float* __restrict__ cw,
                       const float* __restrict__ cb,
                       __hip_bfloat16* __restrict__ xc) {
  long idx = (long)blockIdx.x * blockDim.x + threadIdx.x;
  if (idx >= (long)BH * LL * DD) return;
  int d = idx & 511;
  int p = (int)((idx >> 9) & 1023);
  long b = idx >> 19;
  int h = p >> 5, w = p & 31;
  float acc = cb[d];
  #pragma unroll
  for (int kh = 0; kh < 3; kh++) {
    int hh = h + kh - 1;
    if (hh < 0 || hh > 31) continue;
    #pragma unroll
    for (int kw = 0; kw < 3; kw++) {
      int ww = w + kw - 1;
      if (ww < 0 || ww > 31) continue;
      acc += b2f(xcpre[((b << 10) + (hh << 5) + ww) * (long)DD + d]) * cw[d * 9 + kh * 3 + kw];
    }
  }
  float s = acc / (1.f + __expf(-acc));
  xc[idx] = f2b(s);
}

// ---------------- selective scan: thread per (b,k,d) channel ----------------
// grid (8, 4, B), 64 threads. Dbl row: (b*L+p)*192 + k*48 + {dt[16],B[16],C[16]}
__global__ __launch_bounds__(64) void k_scan(const float* __restrict__ Dbl,
                                             const __hip_bfloat16* __restrict__ xc,
                                             const float* __restrict__ dtw,
                                             const float* __restrict__ dtb,
                                             const float* __restrict__ alog,
                                             const float* __restrict__ Dsp,
                                             __hip_bfloat16* __restrict__ ys) {
  int lane = threadIdx.x;
  int k = blockIdx.y;
  long b = blockIdx.z;
  int d = blockIdx.x * 64 + lane;
  int kd = k * 512 + d;
  float wdt[16], Aa[16], h[16];
  #pragma unroll
  for (int r = 0; r < 16; r++) wdt[r] = dtw[(long)kd * 16 + r];
  #pragma unroll
  for (int n = 0; n < 16; n++) Aa[n] = -__expf(alog[(long)kd * 16 + n]);
  #pragma unroll
  for (int n = 0; n < 16; n++) h[n] = 0.f;
  float dtbias = dtb[kd];
  float Dd = Dsp[kd];
  long ysbase = ((b * 4 + k) * (long)LL) * DD + d;
  for (int t = 0; t < LL; t++) {
    int p;
    if (k == 0) p = t;
    else if (k == 1) p = ((t & 31) << 5) | (t >> 5);
    else if (k == 2) p = 1023 - t;
    else { int l2 = 1023 - t; p = ((l2 & 31) << 5) | (l2 >> 5); }
    const float* row = Dbl + ((b << 10) + p) * 192L + k * 48;
    float u = b2f(xc[(((b << 10) + (long)p) << 9) + d]);
    float dts = dtbias;
    #pragma unroll
    for (int r = 0; r < 16; r++) dts += row[r] * wdt[r];
    float delta = (dts > 20.f) ? dts : log1pf(__expf(dts));
    float du = delta * u;
    float y = 0.f;
    #pragma unroll
    for (int n = 0; n < 16; n++) {
      float w = __expf(delta * Aa[n]);
      h[n] = w * h[n] + du * row[16 + n];
      y += h[n] * row[32 + n];
    }
    ys[ysbase + (long)t * DD] = f2b(y + Dd * u);
  }
}

// ---------------- combine 4 directions + outnorm LN + *silu(z) -> yfin (bf16) ----------------
__global__ __launch_bounds__(256) void k_combine(const __hip_bfloat16* __restrict__ ys,
                                                 const __hip_bfloat16* __restrict__ zb,
                                                 const float* __restrict__ g,
                                                 const float* __restrict__ bb,
                                                 __hip_bfloat16* __restrict__ yfin) {
  __shared__ float sb[4];
  int tid = threadIdx.x;
  long bp = blockIdx.x;            // b*L + p
  long b = bp >> 10;
  int p = (int)(bp & 1023);
  int t1 = ((p & 31) << 5) | (p >> 5);
  float yv[2];
  #pragma unroll
  for (int j = 0; j < 2; j++) {
    int dd = tid + j * 256;
    float y = b2f(ys[((b * 4 + 0) * LL + (long)p) * DD + dd])
            + b2f(ys[((b * 4 + 1) * LL + (long)t1) * DD + dd])
            + b2f(ys[((b * 4 + 2) * LL + (long)(1023 - p)) * DD + dd])
            + b2f(ys[((b * 4 + 3) * LL + (long)(1023 - t1)) * DD + dd]);
    yv[j] = y;
  }
  float mu = block_sum_256(yv[0] + yv[1], sb) * (1.f / DD);
  float d0 = yv[0] - mu, d1 = yv[1] - mu;
  float var = block_sum_256(d0 * d0 + d1 * d1, sb) * (1.f / DD);
  float rs = rsqrtf(var + 1e-5f);
  #pragma unroll
  for (int j = 0; j < 2; j++) {
    int dd = tid + j * 256;
    float v = (yv[j] - mu) * rs * g[dd] + bb[dd];
    float z = b2f(zb[bp * DD + dd]);
    float sz = z / (1.f + __expf(-z));
    yfin[bp * DD + dd] = f2b(v * sz);
  }
}

// ---------------- final sLSTM gating ----------------
__global__ void k_lstm(const float* __restrict__ xbuf, const float* __restrict__ cx,
                       float* __restrict__ out, long n) {
  long i = (long)blockIdx.x * blockDim.x + threadIdx.x;
  if (i >= n) return;
  float o = xbuf[i];
  float F = 1.f / (1.f + __expf(-o));
  float Ct = F * (cx[i] + tanhf(o));
  float Ht = F * tanhf(Ct);
  out[i] = Ht;
  out[n + i] = Ct;
}

extern "C" void kernel_launch(void* const* d_in, const int* in_sizes, int n_in,
                              void* d_out, int out_size, void* d_ws, size_t ws_size,
                              hipStream_t stream) {
  (void)in_sizes; (void)n_in; (void)out_size; (void)ws_size;
  const float* xt        = (const float*)d_in[0];
  const float* hx        = (const float*)d_in[1];
  const float* cx        = (const float*)d_in[2];
  const float* ln1_g     = (const float*)d_in[3];
  const float* ln1_b     = (const float*)d_in[4];
  const float* lin_w     = (const float*)d_in[5];
  const float* lin_b     = (const float*)d_in[6];
  const float* inproj_w  = (const float*)d_in[7];
  const float* conv_w    = (const float*)d_in[8];
  const float* conv_b    = (const float*)d_in[9];
  const float* xproj_w   = (const float*)d_in[10];
  const float* dtproj_w  = (const float*)d_in[11];
  const float* dtproj_b  = (const float*)d_in[12];
  const float* A_logs    = (const float*)d_in[13];
  const float* Ds        = (const float*)d_in[14];
  const float* outnorm_g = (const float*)d_in[15];
  const float* outnorm_b = (const float*)d_in[16];
  const float* outproj_w = (const float*)d_in[17];

  // workspace layout (aliased where lifetimes allow)
  char* base = (char*)d_ws;
  float* xbuf = (float*)base;                        base += (size_t)BH * LL * CC * 4;   // 16.8 MB
  __hip_bfloat16* catn = (__hip_bfloat16*)base;      base += (size_t)BH * LL * 512 * 2;  // 16.8 MB (alias: yfin)
  __hip_bfloat16* xn = (__hip_bfloat16*)base;        base += (size_t)BH * LL * CC * 2;   // 8.4 MB
  char* xpre_region = base;                          base += (size_t)BH * LL * 512 * 2;  // 16.8 MB (xcpre bf16 | Dbl f32)
  __hip_bfloat16* zb = (__hip_bfloat16*)base;        base += (size_t)BH * LL * 512 * 2;  // 16.8 MB
  __hip_bfloat16* xcb = (__hip_bfloat16*)base;       base += (size_t)BH * LL * 512 * 2;  // 16.8 MB
  __hip_bfloat16* ysb = (__hip_bfloat16*)base;       base += (size_t)BH * 4 * LL * 512 * 2; // 67.1 MB
  // bf16 weight copies (converted each launch)
  __hip_bfloat16* lin_wb = (__hip_bfloat16*)base;    base += (size_t)2 * CC * 2 * CC * 2;      // 0.5 MB
  __hip_bfloat16* inproj_wb = (__hip_bfloat16*)base; base += (size_t)2 * 2 * DD * CC * 2;      // 1.0 MB
  __hip_bfloat16* xproj_wb = (__hip_bfloat16*)base;  base += (size_t)2 * 4 * 48 * DD * 2;      // 0.4 MB
  __hip_bfloat16* outproj_wb = (__hip_bfloat16*)base; base += (size_t)2 * CC * DD * 2;         // 0.5 MB
  __hip_bfloat16* xcpre = (__hip_bfloat16*)xpre_region;
  float* Dbl = (float*)xpre_region;                  // written after xcpre is dead
  __hip_bfloat16* yfin = catn;                       // written after catn is dead

  const long n0 = (long)BH * LL * CC;
  const int M = BH * LL;

  // convert MFMA weights to bf16 (both layers at once)
  {
    long n;
    n = 2L * CC * 2 * CC;  k_cvtw<<<(int)((n + 255) / 256), 256, 0, stream>>>(lin_w, lin_wb, n);
    n = 2L * 2 * DD * CC;  k_cvtw<<<(int)((n + 255) / 256), 256, 0, stream>>>(inproj_w, inproj_wb, n);
    n = 2L * 4 * 48 * DD;  k_cvtw<<<(int)((n + 255) / 256), 256, 0, stream>>>(xproj_w, xproj_wb, n);
    n = 2L * CC * DD;      k_cvtw<<<(int)((n + 255) / 256), 256, 0, stream>>>(outproj_w, outproj_wb, n);
  }

  for (int i = 0; i < 2; i++) {
    const float* g1 = ln1_g + i * CC;
    const float* b1 = ln1_b + i * CC;
    if (i == 0) {
      k_ln_cat<<<M, 256, 0, stream>>>(xt, hx, g1, b1, catn);
      gemm_k<0><<<dim3(M / 64, 256 / 64), 64, 0, stream>>>(catn, lin_wb, 512, 256, lin_b, xn, nullptr, nullptr, nullptr);
    } else {
      k_ln<<<M, 256, 0, stream>>>(xbuf, g1, b1, xn);
    }
    // inproj: (M x 256) x (1024 x 256)^T -> xcpre | z
    gemm_k<1><<<dim3(M / 64, 1024 / 64), 64, 0, stream>>>(xn, inproj_wb + (size_t)i * 1024 * 256, 256, 1024,
                                                          nullptr, xcpre, zb, nullptr, nullptr);
    long nc = (long)BH * LL * DD;
    k_conv<<<(int)((nc + 255) / 256), 256, 0, stream>>>(xcpre, conv_w + (size_t)i * DD * 9, conv_b + i * DD, xcb);
    // xproj merged over 4 directions: N = 192, natural position order
    gemm_k<2><<<dim3(M / 64, 192 / 64), 64, 0, stream>>>(xcb, xproj_wb + (size_t)i * 4 * 48 * DD, 512, 192,
                                                         nullptr, nullptr, nullptr, Dbl, nullptr);
    k_scan<<<dim3(8, 4, BH), 64, 0, stream>>>(Dbl, xcb,
                                              dtproj_w + (size_t)i * 4 * 512 * 16,
                                              dtproj_b + (size_t)i * 4 * 512,
                                              A_logs + (size_t)i * 2048 * 16,
                                              Ds + (size_t)i * 2048, ysb);
    k_combine<<<M, 256, 0, stream>>>(ysb, zb, outnorm_g + i * DD, outnorm_b + i * DD, yfin);
    // outproj + residual (layer0: resid = xt input; layer1: in-place on xbuf)
    gemm_k<3><<<dim3(M / 64, 256 / 64), 64, 0, stream>>>(yfin, outproj_wb + (size_t)i * CC * DD, 512, 256,
                                                         nullptr, nullptr, nullptr, xbuf, (i == 0) ? xt : xbuf);
  }
  k_lstm<<<(int)((n0 + 255) / 256), 256, 0, stream>>>(xbuf, cx, (float*)d_out, n0);
}

// Round 3
// 1312.078 us; speedup vs baseline: 2.3012x; 2.3012x over previous
//
#include <hip/hip_runtime.h>
#include <hip/hip_bf16.h>
#include <math.h>

// Problem constants
#define BH 16      // BATCH
#define LL 1024    // L = H*W
#define CC 256     // C
#define DD 512     // DIN
#define NST 16     // N (state dim)
#define NCH 16     // scan chunks
#define TCH 64     // steps per chunk

typedef __attribute__((ext_vector_type(8))) short bf16x8;
typedef __attribute__((ext_vector_type(4))) float f32x4;

__device__ __forceinline__ float b2f(__hip_bfloat16 x) { return __bfloat162float(x); }
__device__ __forceinline__ __hip_bfloat16 f2b(float x) { return __float2bfloat16(x); }

// direction permutation: scan step t -> spatial position p
__device__ __forceinline__ int permp(int k, int t) {
  if (k == 0) return t;
  if (k == 1) return ((t & 31) << 5) | (t >> 5);
  if (k == 2) return 1023 - t;
  int l2 = 1023 - t; return ((l2 & 31) << 5) | (l2 >> 5);
}

// ---------------- block-wide sum over 256 threads (4 waves) ----------------
__device__ __forceinline__ float block_sum_256(float v, float* sb) {
  #pragma unroll
  for (int o = 32; o; o >>= 1) v += __shfl_xor(v, o);
  int w = threadIdx.x >> 6;
  __syncthreads();                       // protect previous use of sb
  if ((threadIdx.x & 63) == 0) sb[w] = v;
  __syncthreads();
  return sb[0] + sb[1] + sb[2] + sb[3];
}

// ---------------- f32 -> bf16 weight conversion ----------------
__global__ void k_cvtw(const float* __restrict__ in, __hip_bfloat16* __restrict__ out, long n) {
  long i = (long)blockIdx.x * blockDim.x + threadIdx.x;
  if (i < n) out[i] = f2b(in[i]);
}

// ---------------- layer0: LN(xt) || LN(hx) -> catn (bf16, B*L x 512) ----------------
__global__ __launch_bounds__(256) void k_ln_cat(const float* __restrict__ xt,
                                                const float* __restrict__ hx,
                                                const float* __restrict__ g,
                                                const float* __restrict__ bb,
                                                __hip_bfloat16* __restrict__ catn) {
  __shared__ float sb[4];
  long row = blockIdx.x;
  int tid = threadIdx.x;
  float xv = xt[row * CC + tid];
  float hv = hx[row * CC + tid];
  float mux = block_sum_256(xv, sb) * (1.f / CC);
  float muh = block_sum_256(hv, sb) * (1.f / CC);
  float dx = xv - mux, dh = hv - muh;
  float vx = block_sum_256(dx * dx, sb) * (1.f / CC);
  float vh = block_sum_256(dh * dh, sb) * (1.f / CC);
  float gg = g[tid], bbv = bb[tid];
  catn[row * 512 + tid]       = f2b(dx * rsqrtf(vx + 1e-5f) * gg + bbv);
  catn[row * 512 + 256 + tid] = f2b(dh * rsqrtf(vh + 1e-5f) * gg + bbv);
}

// ---------------- layer1: LN(xbuf) -> xn (bf16, B*L x 256) ----------------
__global__ __launch_bounds__(256) void k_ln(const float* __restrict__ xbuf,
                                            const float* __restrict__ g,
                                            const float* __restrict__ bb,
                                            __hip_bfloat16* __restrict__ xn) {
  __shared__ float sb[4];
  long row = blockIdx.x;
  int tid = threadIdx.x;
  float xv = xbuf[row * CC + tid];
  float mu = block_sum_256(xv, sb) * (1.f / CC);
  float d = xv - mu;
  float var = block_sum_256(d * d, sb) * (1.f / CC);
  xn[row * CC + tid] = f2b(d * rsqrtf(var + 1e-5f) * g[tid] + bb[tid]);
}

// ---------------- MFMA GEMM: out[r][c] = sum_k A[r][k]*W[c][k] (+epilogue) ----------------
// wave (64 thr) computes 64x64 tile; grid=(M/64, N/64). Wt is N x K (bf16).
template <int EPI>
__global__ __launch_bounds__(64) void gemm_k(const __hip_bfloat16* __restrict__ A,
                                             const __hip_bfloat16* __restrict__ Wt,
                                             int K, int N,
                                             const float* __restrict__ bias,
                                             __hip_bfloat16* outB, __hip_bfloat16* outB2,
                                             float* outF, const float* resid) {
  int lane = threadIdx.x;
  int lr = lane & 15, lh = lane >> 4;
  long r0 = (long)blockIdx.x * 64;
  int c0 = blockIdx.y * 64;
  f32x4 acc[4][4] = {};
  for (int kk = 0; kk < K; kk += 32) {
    bf16x8 af[4], bf[4];
    #pragma unroll
    for (int mi = 0; mi < 4; mi++)
      af[mi] = *reinterpret_cast<const bf16x8*>(A + (r0 + mi * 16 + lr) * (long)K + kk + lh * 8);
    #pragma unroll
    for (int ci = 0; ci < 4; ci++)
      bf[ci] = *reinterpret_cast<const bf16x8*>(Wt + ((long)(c0 + ci * 16 + lr)) * (long)K + kk + lh * 8);
    #pragma unroll
    for (int mi = 0; mi < 4; mi++)
      #pragma unroll
      for (int ci = 0; ci < 4; ci++)
        acc[mi][ci] = __builtin_amdgcn_mfma_f32_16x16x32_bf16(af[mi], bf[ci], acc[mi][ci], 0, 0, 0);
  }
  #pragma unroll
  for (int mi = 0; mi < 4; mi++)
    #pragma unroll
    for (int ci = 0; ci < 4; ci++)
      #pragma unroll
      for (int r = 0; r < 4; r++) {
        long row = r0 + mi * 16 + lh * 4 + r;
        int col = c0 + ci * 16 + lr;
        float v = acc[mi][ci][r];
        if (EPI == 0) outB[row * (long)N + col] = f2b(v + bias[col]);
        if (EPI == 1) {
          if (col < 512) outB[row * 512 + col] = f2b(v);
          else           outB2[row * 512 + (col - 512)] = f2b(v);
        }
        if (EPI == 2) outF[row * (long)N + col] = v;
        if (EPI == 3) outF[row * (long)N + col] = v + resid[row * (long)N + col];
      }
}

// ---------------- depthwise 3x3 conv + bias + SiLU ----------------
__global__ void k_conv(const __hip_bfloat16* __restrict__ xcpre,
                       const float* __restrict__ cw,
                       const float* __restrict__ cb,
                       __hip_bfloat16* __restrict__ xc) {
  long idx = (long)blockIdx.x * blockDim.x + threadIdx.x;
  if (idx >= (long)BH * LL * DD) return;
  int d = idx & 511;
  int p = (int)((idx >> 9) & 1023);
  long b = idx >> 19;
  int h = p >> 5, w = p & 31;
  float acc = cb[d];
  #pragma unroll
  for (int kh = 0; kh < 3; kh++) {
    int hh = h + kh - 1;
    if (hh < 0 || hh > 31) continue;
    #pragma unroll
    for (int kw = 0; kw < 3; kw++) {
      int ww = w + kw - 1;
      if (ww < 0 || ww > 31) continue;
      acc += b2f(xcpre[((b << 10) + (hh << 5) + ww) * (long)DD + d]) * cw[d * 9 + kh * 3 + kw];
    }
  }
  float s = acc / (1.f + __expf(-acc));
  xc[idx] = f2b(s);
}

// ============== chunked selective scan ==============
// Channel ch = (b*4+k)*512+d  (32768 channels); chunk c of TCH steps.
// hbuf layout: [c][ch][n] f32  (pass1 writes local h_end; pass2a rewrites to h_start)
// sdbuf layout: [c][ch] f32   (sum of delta over chunk)

// ---- pass 1: per-chunk local scan from h=0; store h_end + sum(delta) ----
__global__ __launch_bounds__(64) void k_scan1(const float* __restrict__ Dbl,
                                              const __hip_bfloat16* __restrict__ xc,
                                              const float* __restrict__ dtw,
                                              const float* __restrict__ dtb,
                                              const float* __restrict__ alog,
                                              float* __restrict__ hbuf,
                                              float* __restrict__ sdbuf) {
  int lane = threadIdx.x;
  int k = blockIdx.y;
  int bz = blockIdx.z; int b = bz >> 4; int c = bz & (NCH - 1);
  int d = blockIdx.x * 64 + lane;
  int kd = (k << 9) + d;
  int ch = ((b * 4 + k) << 9) + d;
  float wdt[16], Aa[16], h[16];
  #pragma unroll
  for (int r = 0; r < 16; r++) wdt[r] = dtw[(long)kd * 16 + r];
  #pragma unroll
  for (int n = 0; n < 16; n++) { Aa[n] = -__expf(alog[(long)kd * 16 + n]); h[n] = 0.f; }
  float dtbias = dtb[kd];
  float sd = 0.f;
  for (int tt = 0; tt < TCH; tt++) {
    int t = c * TCH + tt;
    int p = permp(k, t);
    const f32x4* row = reinterpret_cast<const f32x4*>(Dbl + ((b << 10) + p) * 192L + k * 48);
    f32x4 dv[4], Bv[4];
    #pragma unroll
    for (int j = 0; j < 4; j++) dv[j] = row[j];
    #pragma unroll
    for (int j = 0; j < 4; j++) Bv[j] = row[4 + j];
    float u = b2f(xc[(((b << 10) + (long)p) << 9) + d]);
    float dts = dtbias;
    #pragma unroll
    for (int j = 0; j < 4; j++)
      #pragma unroll
      for (int q = 0; q < 4; q++) dts += dv[j][q] * wdt[j * 4 + q];
    float delta = (dts > 20.f) ? dts : log1pf(__expf(dts));
    sd += delta;
    float du = delta * u;
    #pragma unroll
    for (int n = 0; n < 16; n++)
      h[n] = __expf(delta * Aa[n]) * h[n] + du * Bv[n >> 2][n & 3];
  }
  f32x4* hw = reinterpret_cast<f32x4*>(hbuf + ((size_t)c * 32768 + ch) * 16);
  #pragma unroll
  for (int j = 0; j < 4; j++) {
    f32x4 v; v[0] = h[j * 4]; v[1] = h[j * 4 + 1]; v[2] = h[j * 4 + 2]; v[3] = h[j * 4 + 3];
    hw[j] = v;
  }
  sdbuf[(size_t)c * 32768 + ch] = sd;
}

// ---- pass 2a: combine chunk transitions sequentially; hbuf becomes h_start ----
// thread per (ch, n): tid = ch*16 + n  (perfectly coalesced on hbuf)
__global__ __launch_bounds__(256) void k_scan2a(const float* __restrict__ alog,
                                                const float* __restrict__ sdbuf,
                                                float* __restrict__ hbuf) {
  int tid = blockIdx.x * 256 + threadIdx.x;      // 0 .. 524287
  int ch = tid >> 4;
  int n = tid & 15;
  int kd = ch & 2047;
  float A = -__expf(alog[(long)kd * 16 + n]);
  float s = 0.f;
  #pragma unroll 4
  for (int c = 0; c < NCH; c++) {
    size_t idx = (size_t)c * 524288 + tid;
    float tmp = hbuf[idx];
    hbuf[idx] = s;
    s = __expf(A * sdbuf[(size_t)c * 32768 + ch]) * s + tmp;
  }
}

// ---- pass 2b: re-run each chunk from h_start, emitting ys ----
__global__ __launch_bounds__(64) void k_scan2b(const float* __restrict__ Dbl,
                                               const __hip_bfloat16* __restrict__ xc,
                                               const float* __restrict__ dtw,
                                               const float* __restrict__ dtb,
                                               const float* __restrict__ alog,
                                               const float* __restrict__ Dsp,
                                               const float* __restrict__ hbuf,
                                               __hip_bfloat16* __restrict__ ys) {
  int lane = threadIdx.x;
  int k = blockIdx.y;
  int bz = blockIdx.z; int b = bz >> 4; int c = bz & (NCH - 1);
  int d = blockIdx.x * 64 + lane;
  int kd = (k << 9) + d;
  int ch = ((b * 4 + k) << 9) + d;
  float wdt[16], Aa[16], h[16];
  #pragma unroll
  for (int r = 0; r < 16; r++) wdt[r] = dtw[(long)kd * 16 + r];
  #pragma unroll
  for (int n = 0; n < 16; n++) Aa[n] = -__expf(alog[(long)kd * 16 + n]);
  const f32x4* hr = reinterpret_cast<const f32x4*>(hbuf + ((size_t)c * 32768 + ch) * 16);
  #pragma unroll
  for (int j = 0; j < 4; j++) {
    f32x4 v = hr[j];
    h[j * 4] = v[0]; h[j * 4 + 1] = v[1]; h[j * 4 + 2] = v[2]; h[j * 4 + 3] = v[3];
  }
  float dtbias = dtb[kd];
  float Dd = Dsp[kd];
  long ysbase = ((b * 4 + k) * (long)LL) * DD + d;
  for (int tt = 0; tt < TCH; tt++) {
    int t = c * TCH + tt;
    int p = permp(k, t);
    const f32x4* row = reinterpret_cast<const f32x4*>(Dbl + ((b << 10) + p) * 192L + k * 48);
    f32x4 dv[4], Bv[4], Cv[4];
    #pragma unroll
    for (int j = 0; j < 4; j++) dv[j] = row[j];
    #pragma unroll
    for (int j = 0; j < 4; j++) Bv[j] = row[4 + j];
    #pragma unroll
    for (int j = 0; j < 4; j++) Cv[j] = row[8 + j];
    float u = b2f(xc[(((b << 10) + (long)p) << 9) + d]);
    float dts = dtbias;
    #pragma unroll
    for (int j = 0; j < 4; j++)
      #pragma unroll
      for (int q = 0; q < 4; q++) dts += dv[j][q] * wdt[j * 4 + q];
    float delta = (dts > 20.f) ? dts : log1pf(__expf(dts));
    float du = delta * u;
    float y = 0.f;
    #pragma unroll
    for (int n = 0; n < 16; n++) {
      h[n] = __expf(delta * Aa[n]) * h[n] + du * Bv[n >> 2][n & 3];
      y += h[n] * Cv[n >> 2][n & 3];
    }
    ys[ysbase + (long)t * DD] = f2b(y + Dd * u);
  }
}

// ---------------- combine 4 directions + outnorm LN + *silu(z) -> yfin (bf16) ----------------
__global__ __launch_bounds__(256) void k_combine(const __hip_bfloat16* __restrict__ ys,
                                                 const __hip_bfloat16* __restrict__ zb,
                                                 const float* __restrict__ g,
                                                 const float* __restrict__ bb,
                                                 __hip_bfloat16* __restrict__ yfin) {
  __shared__ float sb[4];
  int tid = threadIdx.x;
  long bp = blockIdx.x;            // b*L + p
  long b = bp >> 10;
  int p = (int)(bp & 1023);
  int t1 = ((p & 31) << 5) | (p >> 5);
  float yv[2];
  #pragma unroll
  for (int j = 0; j < 2; j++) {
    int dd = tid + j * 256;
    float y = b2f(ys[((b * 4 + 0) * LL + (long)p) * DD + dd])
            + b2f(ys[((b * 4 + 1) * LL + (long)t1) * DD + dd])
            + b2f(ys[((b * 4 + 2) * LL + (long)(1023 - p)) * DD + dd])
            + b2f(ys[((b * 4 + 3) * LL + (long)(1023 - t1)) * DD + dd]);
    yv[j] = y;
  }
  float mu = block_sum_256(yv[0] + yv[1], sb) * (1.f / DD);
  float d0 = yv[0] - mu, d1 = yv[1] - mu;
  float var = block_sum_256(d0 * d0 + d1 * d1, sb) * (1.f / DD);
  float rs = rsqrtf(var + 1e-5f);
  #pragma unroll
  for (int j = 0; j < 2; j++) {
    int dd = tid + j * 256;
    float v = (yv[j] - mu) * rs * g[dd] + bb[dd];
    float z = b2f(zb[bp * DD + dd]);
    float sz = z / (1.f + __expf(-z));
    yfin[bp * DD + dd] = f2b(v * sz);
  }
}

// ---------------- final sLSTM gating ----------------
__global__ void k_lstm(const float* __restrict__ xbuf, const float* __restrict__ cx,
                       float* __restrict__ out, long n) {
  long i = (long)blockIdx.x * blockDim.x + threadIdx.x;
  if (i >= n) return;
  float o = xbuf[i];
  float F = 1.f / (1.f + __expf(-o));
  float Ct = F * (cx[i] + tanhf(o));
  float Ht = F * tanhf(Ct);
  out[i] = Ht;
  out[n + i] = Ct;
}

extern "C" void kernel_launch(void* const* d_in, const int* in_sizes, int n_in,
                              void* d_out, int out_size, void* d_ws, size_t ws_size,
                              hipStream_t stream) {
  (void)in_sizes; (void)n_in; (void)out_size; (void)ws_size;
  const float* xt        = (const float*)d_in[0];
  const float* hx        = (const float*)d_in[1];
  const float* cx        = (const float*)d_in[2];
  const float* ln1_g     = (const float*)d_in[3];
  const float* ln1_b     = (const float*)d_in[4];
  const float* lin_w     = (const float*)d_in[5];
  const float* lin_b     = (const float*)d_in[6];
  const float* inproj_w  = (const float*)d_in[7];
  const float* conv_w    = (const float*)d_in[8];
  const float* conv_b    = (const float*)d_in[9];
  const float* xproj_w   = (const float*)d_in[10];
  const float* dtproj_w  = (const float*)d_in[11];
  const float* dtproj_b  = (const float*)d_in[12];
  const float* A_logs    = (const float*)d_in[13];
  const float* Ds        = (const float*)d_in[14];
  const float* outnorm_g = (const float*)d_in[15];
  const float* outnorm_b = (const float*)d_in[16];
  const float* outproj_w = (const float*)d_in[17];

  // workspace layout (aliased where lifetimes allow)
  char* base = (char*)d_ws;
  float* xbuf = (float*)base;                        base += (size_t)BH * LL * CC * 4;   // 16.8 MB
  __hip_bfloat16* catn = (__hip_bfloat16*)base;      base += (size_t)BH * LL * 512 * 2;  // 16.8 MB (alias: yfin)
  __hip_bfloat16* xn = (__hip_bfloat16*)base;        base += (size_t)BH * LL * CC * 2;   // 8.4 MB
  char* xpre_region = base;                          base += (size_t)BH * LL * 512 * 2;  // 16.8 MB (xcpre bf16 | Dbl f32)
  __hip_bfloat16* zb = (__hip_bfloat16*)base;        base += (size_t)BH * LL * 512 * 2;  // 16.8 MB
  __hip_bfloat16* xcb = (__hip_bfloat16*)base;       base += (size_t)BH * LL * 512 * 2;  // 16.8 MB
  __hip_bfloat16* ysb = (__hip_bfloat16*)base;       base += (size_t)BH * 4 * LL * 512 * 2; // 67.1 MB
  // bf16 weight copies (converted each launch)
  __hip_bfloat16* lin_wb = (__hip_bfloat16*)base;    base += (size_t)2 * CC * 2 * CC * 2;      // 0.5 MB
  __hip_bfloat16* inproj_wb = (__hip_bfloat16*)base; base += (size_t)2 * 2 * DD * CC * 2;      // 1.0 MB
  __hip_bfloat16* xproj_wb = (__hip_bfloat16*)base;  base += (size_t)2 * 4 * 48 * DD * 2;      // 0.4 MB
  __hip_bfloat16* outproj_wb = (__hip_bfloat16*)base; base += (size_t)2 * CC * DD * 2;         // 0.5 MB
  // chunked-scan state
  float* hbuf = (float*)base;                        base += (size_t)NCH * 32768 * 16 * 4;     // 33.6 MB
  float* sdbuf = (float*)base;                       base += (size_t)NCH * 32768 * 4;          // 2.1 MB
  __hip_bfloat16* xcpre = (__hip_bfloat16*)xpre_region;
  float* Dbl = (float*)xpre_region;                  // written after xcpre is dead
  __hip_bfloat16* yfin = catn;                       // written after catn is dead

  const long n0 = (long)BH * LL * CC;
  const int M = BH * LL;

  // convert MFMA weights to bf16 (both layers at once)
  {
    long n;
    n = 2L * CC * 2 * CC;  k_cvtw<<<(int)((n + 255) / 256), 256, 0, stream>>>(lin_w, lin_wb, n);
    n = 2L * 2 * DD * CC;  k_cvtw<<<(int)((n + 255) / 256), 256, 0, stream>>>(inproj_w, inproj_wb, n);
    n = 2L * 4 * 48 * DD;  k_cvtw<<<(int)((n + 255) / 256), 256, 0, stream>>>(xproj_w, xproj_wb, n);
    n = 2L * CC * DD;      k_cvtw<<<(int)((n + 255) / 256), 256, 0, stream>>>(outproj_w, outproj_wb, n);
  }

  for (int i = 0; i < 2; i++) {
    const float* g1 = ln1_g + i * CC;
    const float* b1 = ln1_b + i * CC;
    if (i == 0) {
      k_ln_cat<<<M, 256, 0, stream>>>(xt, hx, g1, b1, catn);
      gemm_k<0><<<dim3(M / 64, 256 / 64), 64, 0, stream>>>(catn, lin_wb, 512, 256, lin_b, xn, nullptr, nullptr, nullptr);
    } else {
      k_ln<<<M, 256, 0, stream>>>(xbuf, g1, b1, xn);
    }
    // inproj: (M x 256) x (1024 x 256)^T -> xcpre | z
    gemm_k<1><<<dim3(M / 64, 1024 / 64), 64, 0, stream>>>(xn, inproj_wb + (size_t)i * 1024 * 256, 256, 1024,
                                                          nullptr, xcpre, zb, nullptr, nullptr);
    long nc = (long)BH * LL * DD;
    k_conv<<<(int)((nc + 255) / 256), 256, 0, stream>>>(xcpre, conv_w + (size_t)i * DD * 9, conv_b + i * DD, xcb);
    // xproj merged over 4 directions: N = 192, natural position order
    gemm_k<2><<<dim3(M / 64, 192 / 64), 64, 0, stream>>>(xcb, xproj_wb + (size_t)i * 4 * 48 * DD, 512, 192,
                                                         nullptr, nullptr, nullptr, Dbl, nullptr);
    // chunked scan
    const float* dtw_i = dtproj_w + (size_t)i * 4 * 512 * 16;
    const float* dtb_i = dtproj_b + (size_t)i * 4 * 512;
    const float* alog_i = A_logs + (size_t)i * 2048 * 16;
    const float* Ds_i = Ds + (size_t)i * 2048;
    k_scan1<<<dim3(8, 4, BH * NCH), 64, 0, stream>>>(Dbl, xcb, dtw_i, dtb_i, alog_i, hbuf, sdbuf);
    k_scan2a<<<524288 / 256, 256, 0, stream>>>(alog_i, sdbuf, hbuf);
    k_scan2b<<<dim3(8, 4, BH * NCH), 64, 0, stream>>>(Dbl, xcb, dtw_i, dtb_i, alog_i, Ds_i, hbuf, ysb);
    k_combine<<<M, 256, 0, stream>>>(ysb, zb, outnorm_g + i * DD, outnorm_b + i * DD, yfin);
    // outproj + residual (layer0: resid = xt input; layer1: in-place on xbuf)
    gemm_k<3><<<dim3(M / 64, 256 / 64), 64, 0, stream>>>(yfin, outproj_wb + (size_t)i * CC * DD, 512, 256,
                                                         nullptr, nullptr, nullptr, xbuf, (i == 0) ? xt : xbuf);
  }
  k_lstm<<<(int)((n0 + 255) / 256), 256, 0, stream>>>(xbuf, cx, (float*)d_out, n0);
}

// Round 4
// 966.642 us; speedup vs baseline: 3.1235x; 1.3574x over previous
//
#include <hip/hip_runtime.h>
#include <hip/hip_bf16.h>
#include <math.h>

// Problem constants
#define BH 16      // BATCH
#define LL 1024    // L = H*W
#define CC 256     // C
#define DD 512     // DIN
#define NST 16     // N (state dim)
#define NCH 16     // scan chunks
#define TCH 64     // steps per chunk

typedef __attribute__((ext_vector_type(8))) short bf16x8;
typedef __attribute__((ext_vector_type(4))) float f32x4;

__device__ __forceinline__ float b2f(__hip_bfloat16 x) { return __bfloat162float(x); }
__device__ __forceinline__ __hip_bfloat16 f2b(float x) { return __float2bfloat16(x); }

__device__ __forceinline__ f32x4 exp4(f32x4 x) {
  f32x4 r; r[0] = __expf(x[0]); r[1] = __expf(x[1]); r[2] = __expf(x[2]); r[3] = __expf(x[3]); return r;
}
__device__ __forceinline__ float hsum4(f32x4 v) { return (v[0] + v[1]) + (v[2] + v[3]); }
__device__ __forceinline__ f32x4 splat4(float s) { f32x4 v = {s, s, s, s}; return v; }

// direction permutation: scan step t -> spatial position p
__device__ __forceinline__ int permp(int k, int t) {
  if (k == 0) return t;
  if (k == 1) return ((t & 31) << 5) | (t >> 5);
  if (k == 2) return 1023 - t;
  int l2 = 1023 - t; return ((l2 & 31) << 5) | (l2 >> 5);
}

// ---------------- block-wide sum over 256 threads (4 waves) ----------------
__device__ __forceinline__ float block_sum_256(float v, float* sb) {
  #pragma unroll
  for (int o = 32; o; o >>= 1) v += __shfl_xor(v, o);
  int w = threadIdx.x >> 6;
  __syncthreads();                       // protect previous use of sb
  if ((threadIdx.x & 63) == 0) sb[w] = v;
  __syncthreads();
  return sb[0] + sb[1] + sb[2] + sb[3];
}

// ---------------- f32 -> bf16 weight conversion ----------------
__global__ void k_cvtw(const float* __restrict__ in, __hip_bfloat16* __restrict__ out, long n) {
  long i = (long)blockIdx.x * blockDim.x + threadIdx.x;
  if (i < n) out[i] = f2b(in[i]);
}

// ---------------- layer0: LN(xt) || LN(hx) -> catn (bf16, B*L x 512) ----------------
__global__ __launch_bounds__(256) void k_ln_cat(const float* __restrict__ xt,
                                                const float* __restrict__ hx,
                                                const float* __restrict__ g,
                                                const float* __restrict__ bb,
                                                __hip_bfloat16* __restrict__ catn) {
  __shared__ float sb[4];
  long row = blockIdx.x;
  int tid = threadIdx.x;
  float xv = xt[row * CC + tid];
  float hv = hx[row * CC + tid];
  float mux = block_sum_256(xv, sb) * (1.f / CC);
  float muh = block_sum_256(hv, sb) * (1.f / CC);
  float dx = xv - mux, dh = hv - muh;
  float vx = block_sum_256(dx * dx, sb) * (1.f / CC);
  float vh = block_sum_256(dh * dh, sb) * (1.f / CC);
  float gg = g[tid], bbv = bb[tid];
  catn[row * 512 + tid]       = f2b(dx * rsqrtf(vx + 1e-5f) * gg + bbv);
  catn[row * 512 + 256 + tid] = f2b(dh * rsqrtf(vh + 1e-5f) * gg + bbv);
}

// ---------------- layer1: LN(xbuf) -> xn (bf16, B*L x 256) ----------------
__global__ __launch_bounds__(256) void k_ln(const float* __restrict__ xbuf,
                                            const float* __restrict__ g,
                                            const float* __restrict__ bb,
                                            __hip_bfloat16* __restrict__ xn) {
  __shared__ float sb[4];
  long row = blockIdx.x;
  int tid = threadIdx.x;
  float xv = xbuf[row * CC + tid];
  float mu = block_sum_256(xv, sb) * (1.f / CC);
  float d = xv - mu;
  float var = block_sum_256(d * d, sb) * (1.f / CC);
  xn[row * CC + tid] = f2b(d * rsqrtf(var + 1e-5f) * g[tid] + bb[tid]);
}

// ---------------- MFMA GEMM: out[r][c] = sum_k A[r][k]*W[c][k] (+epilogue) ----------------
// wave (64 thr) computes 64x64 tile; grid=(M/64, N/64). Wt is N x K (bf16).
template <int EPI>
__global__ __launch_bounds__(64) void gemm_k(const __hip_bfloat16* __restrict__ A,
                                             const __hip_bfloat16* __restrict__ Wt,
                                             int K, int N,
                                             const float* __restrict__ bias,
                                             __hip_bfloat16* outB, __hip_bfloat16* outB2,
                                             float* outF, const float* resid) {
  int lane = threadIdx.x;
  int lr = lane & 15, lh = lane >> 4;
  long r0 = (long)blockIdx.x * 64;
  int c0 = blockIdx.y * 64;
  f32x4 acc[4][4] = {};
  for (int kk = 0; kk < K; kk += 32) {
    bf16x8 af[4], bf[4];
    #pragma unroll
    for (int mi = 0; mi < 4; mi++)
      af[mi] = *reinterpret_cast<const bf16x8*>(A + (r0 + mi * 16 + lr) * (long)K + kk + lh * 8);
    #pragma unroll
    for (int ci = 0; ci < 4; ci++)
      bf[ci] = *reinterpret_cast<const bf16x8*>(Wt + ((long)(c0 + ci * 16 + lr)) * (long)K + kk + lh * 8);
    #pragma unroll
    for (int mi = 0; mi < 4; mi++)
      #pragma unroll
      for (int ci = 0; ci < 4; ci++)
        acc[mi][ci] = __builtin_amdgcn_mfma_f32_16x16x32_bf16(af[mi], bf[ci], acc[mi][ci], 0, 0, 0);
  }
  #pragma unroll
  for (int mi = 0; mi < 4; mi++)
    #pragma unroll
    for (int ci = 0; ci < 4; ci++)
      #pragma unroll
      for (int r = 0; r < 4; r++) {
        long row = r0 + mi * 16 + lh * 4 + r;
        int col = c0 + ci * 16 + lr;
        float v = acc[mi][ci][r];
        if (EPI == 0) outB[row * (long)N + col] = f2b(v + bias[col]);
        if (EPI == 1) {
          if (col < 512) outB[row * 512 + col] = f2b(v);
          else           outB2[row * 512 + (col - 512)] = f2b(v);
        }
        if (EPI == 2) outF[row * (long)N + col] = v;
        if (EPI == 3) outF[row * (long)N + col] = v + resid[row * (long)N + col];
      }
}

// ---------------- depthwise 3x3 conv + bias + SiLU ----------------
__global__ void k_conv(const __hip_bfloat16* __restrict__ xcpre,
                       const float* __restrict__ cw,
                       const float* __restrict__ cb,
                       __hip_bfloat16* __restrict__ xc) {
  long idx = (long)blockIdx.x * blockDim.x + threadIdx.x;
  if (idx >= (long)BH * LL * DD) return;
  int d = idx & 511;
  int p = (int)((idx >> 9) & 1023);
  long b = idx >> 19;
  int h = p >> 5, w = p & 31;
  float acc = cb[d];
  #pragma unroll
  for (int kh = 0; kh < 3; kh++) {
    int hh = h + kh - 1;
    if (hh < 0 || hh > 31) continue;
    #pragma unroll
    for (int kw = 0; kw < 3; kw++) {
      int ww = w + kw - 1;
      if (ww < 0 || ww > 31) continue;
      acc += b2f(xcpre[((b << 10) + (hh << 5) + ww) * (long)DD + d]) * cw[d * 9 + kh * 3 + kw];
    }
  }
  float s = acc / (1.f + __expf(-acc));
  xc[idx] = f2b(s);
}

// ============== chunked selective scan ==============
// Channel ch = (b*4+k)*512+d  (32768 channels); chunk c of TCH steps.
// hbuf layout: [c][ch][n] f32  (pass1 writes local h_end; pass2a rewrites to h_start)
// sdbuf layout: [c][ch] f32   (sum of delta over chunk)
// All per-thread state in NAMED f32x4s (no indexable arrays -> guaranteed registers).

// ---- pass 1: per-chunk local scan from h=0; store h_end + sum(delta) ----
__global__ __launch_bounds__(64, 4) void k_scan1(const float* __restrict__ Dbl,
                                                 const __hip_bfloat16* __restrict__ xc,
                                                 const float* __restrict__ dtw,
                                                 const float* __restrict__ dtb,
                                                 const float* __restrict__ alog,
                                                 float* __restrict__ hbuf,
                                                 float* __restrict__ sdbuf) {
  int lane = threadIdx.x;
  int k = blockIdx.y;
  int bz = blockIdx.z; int b = bz >> 4; int c = bz & (NCH - 1);
  int d = blockIdx.x * 64 + lane;
  int kd = (k << 9) + d;
  int ch = ((b * 4 + k) << 9) + d;
  const f32x4* wv = reinterpret_cast<const f32x4*>(dtw + (long)kd * 16);
  f32x4 w0 = wv[0], w1 = wv[1], w2 = wv[2], w3 = wv[3];
  const f32x4* av = reinterpret_cast<const f32x4*>(alog + (long)kd * 16);
  f32x4 A0 = -exp4(av[0]), A1 = -exp4(av[1]), A2 = -exp4(av[2]), A3 = -exp4(av[3]);
  f32x4 h0 = splat4(0.f), h1 = h0, h2 = h0, h3 = h0;
  float dtbias = dtb[kd];
  float sd = 0.f;
  for (int tt = 0; tt < TCH; tt++) {
    int t = c * TCH + tt;
    int p = permp(k, t);
    const f32x4* row = reinterpret_cast<const f32x4*>(Dbl + ((b << 10) + p) * 192L + k * 48);
    f32x4 r0 = row[0], r1 = row[1], r2 = row[2], r3 = row[3];
    f32x4 B0 = row[4], B1 = row[5], B2 = row[6], B3 = row[7];
    float u = b2f(xc[(((b << 10) + (long)p) << 9) + d]);
    f32x4 dacc = r0 * w0 + r1 * w1 + r2 * w2 + r3 * w3;
    float dts = dtbias + hsum4(dacc);
    float delta = fmaxf(dts, 0.f) + __logf(1.f + __expf(-fabsf(dts)));
    sd += delta;
    f32x4 dl = splat4(delta), dus = splat4(delta * u);
    h0 = exp4(dl * A0) * h0 + dus * B0;
    h1 = exp4(dl * A1) * h1 + dus * B1;
    h2 = exp4(dl * A2) * h2 + dus * B2;
    h3 = exp4(dl * A3) * h3 + dus * B3;
  }
  f32x4* hw = reinterpret_cast<f32x4*>(hbuf + ((size_t)c * 32768 + ch) * 16);
  hw[0] = h0; hw[1] = h1; hw[2] = h2; hw[3] = h3;
  sdbuf[(size_t)c * 32768 + ch] = sd;
}

// ---- pass 2a: combine chunk transitions sequentially; hbuf becomes h_start ----
// thread per (ch, n): tid = ch*16 + n  (perfectly coalesced on hbuf)
__global__ __launch_bounds__(256) void k_scan2a(const float* __restrict__ alog,
                                                const float* __restrict__ sdbuf,
                                                float* __restrict__ hbuf) {
  int tid = blockIdx.x * 256 + threadIdx.x;      // 0 .. 524287
  int ch = tid >> 4;
  int n = tid & 15;
  int kd = ch & 2047;
  float A = -__expf(alog[(long)kd * 16 + n]);
  float s = 0.f;
  #pragma unroll 4
  for (int c = 0; c < NCH; c++) {
    size_t idx = (size_t)c * 524288 + tid;
    float tmp = hbuf[idx];
    hbuf[idx] = s;
    s = __expf(A * sdbuf[(size_t)c * 32768 + ch]) * s + tmp;
  }
}

// ---- pass 2b: re-run each chunk from h_start, emitting ys ----
__global__ __launch_bounds__(64, 4) void k_scan2b(const float* __restrict__ Dbl,
                                                  const __hip_bfloat16* __restrict__ xc,
                                                  const float* __restrict__ dtw,
                                                  const float* __restrict__ dtb,
                                                  const float* __restrict__ alog,
                                                  const float* __restrict__ Dsp,
                                                  const float* __restrict__ hbuf,
                                                  __hip_bfloat16* __restrict__ ys) {
  int lane = threadIdx.x;
  int k = blockIdx.y;
  int bz = blockIdx.z; int b = bz >> 4; int c = bz & (NCH - 1);
  int d = blockIdx.x * 64 + lane;
  int kd = (k << 9) + d;
  int ch = ((b * 4 + k) << 9) + d;
  const f32x4* wv = reinterpret_cast<const f32x4*>(dtw + (long)kd * 16);
  f32x4 w0 = wv[0], w1 = wv[1], w2 = wv[2], w3 = wv[3];
  const f32x4* av = reinterpret_cast<const f32x4*>(alog + (long)kd * 16);
  f32x4 A0 = -exp4(av[0]), A1 = -exp4(av[1]), A2 = -exp4(av[2]), A3 = -exp4(av[3]);
  const f32x4* hr = reinterpret_cast<const f32x4*>(hbuf + ((size_t)c * 32768 + ch) * 16);
  f32x4 h0 = hr[0], h1 = hr[1], h2 = hr[2], h3 = hr[3];
  float dtbias = dtb[kd];
  float Dd = Dsp[kd];
  long ysbase = ((b * 4 + k) * (long)LL) * DD + d;
  for (int tt = 0; tt < TCH; tt++) {
    int t = c * TCH + tt;
    int p = permp(k, t);
    const f32x4* row = reinterpret_cast<const f32x4*>(Dbl + ((b << 10) + p) * 192L + k * 48);
    f32x4 r0 = row[0], r1 = row[1], r2 = row[2], r3 = row[3];
    f32x4 B0 = row[4], B1 = row[5], B2 = row[6], B3 = row[7];
    f32x4 C0 = row[8], C1 = row[9], C2 = row[10], C3 = row[11];
    float u = b2f(xc[(((b << 10) + (long)p) << 9) + d]);
    f32x4 dacc = r0 * w0 + r1 * w1 + r2 * w2 + r3 * w3;
    float dts = dtbias + hsum4(dacc);
    float delta = fmaxf(dts, 0.f) + __logf(1.f + __expf(-fabsf(dts)));
    f32x4 dl = splat4(delta), dus = splat4(delta * u);
    h0 = exp4(dl * A0) * h0 + dus * B0;
    h1 = exp4(dl * A1) * h1 + dus * B1;
    h2 = exp4(dl * A2) * h2 + dus * B2;
    h3 = exp4(dl * A3) * h3 + dus * B3;
    float y = hsum4(h0 * C0 + h1 * C1 + h2 * C2 + h3 * C3);
    ys[ysbase + (long)t * DD] = f2b(y + Dd * u);
  }
}

// ---------------- combine 4 directions + outnorm LN + *silu(z) -> yfin (bf16) ----------------
__global__ __launch_bounds__(256) void k_combine(const __hip_bfloat16* __restrict__ ys,
                                                 const __hip_bfloat16* __restrict__ zb,
                                                 const float* __restrict__ g,
                                                 const float* __restrict__ bb,
                                                 __hip_bfloat16* __restrict__ yfin) {
  __shared__ float sb[4];
  int tid = threadIdx.x;
  long bp = blockIdx.x;            // b*L + p
  long b = bp >> 10;
  int p = (int)(bp & 1023);
  int t1 = ((p & 31) << 5) | (p >> 5);
  float yv[2];
  #pragma unroll
  for (int j = 0; j < 2; j++) {
    int dd = tid + j * 256;
    float y = b2f(ys[((b * 4 + 0) * LL + (long)p) * DD + dd])
            + b2f(ys[((b * 4 + 1) * LL + (long)t1) * DD + dd])
            + b2f(ys[((b * 4 + 2) * LL + (long)(1023 - p)) * DD + dd])
            + b2f(ys[((b * 4 + 3) * LL + (long)(1023 - t1)) * DD + dd]);
    yv[j] = y;
  }
  float mu = block_sum_256(yv[0] + yv[1], sb) * (1.f / DD);
  float d0 = yv[0] - mu, d1 = yv[1] - mu;
  float var = block_sum_256(d0 * d0 + d1 * d1, sb) * (1.f / DD);
  float rs = rsqrtf(var + 1e-5f);
  #pragma unroll
  for (int j = 0; j < 2; j++) {
    int dd = tid + j * 256;
    float v = (yv[j] - mu) * rs * g[dd] + bb[dd];
    float z = b2f(zb[bp * DD + dd]);
    float sz = z / (1.f + __expf(-z));
    yfin[bp * DD + dd] = f2b(v * sz);
  }
}

// ---------------- final sLSTM gating ----------------
__global__ void k_lstm(const float* __restrict__ xbuf, const float* __restrict__ cx,
                       float* __restrict__ out, long n) {
  long i = (long)blockIdx.x * blockDim.x + threadIdx.x;
  if (i >= n) return;
  float o = xbuf[i];
  float F = 1.f / (1.f + __expf(-o));
  float Ct = F * (cx[i] + tanhf(o));
  float Ht = F * tanhf(Ct);
  out[i] = Ht;
  out[n + i] = Ct;
}

extern "C" void kernel_launch(void* const* d_in, const int* in_sizes, int n_in,
                              void* d_out, int out_size, void* d_ws, size_t ws_size,
                              hipStream_t stream) {
  (void)in_sizes; (void)n_in; (void)out_size; (void)ws_size;
  const float* xt        = (const float*)d_in[0];
  const float* hx        = (const float*)d_in[1];
  const float* cx        = (const float*)d_in[2];
  const float* ln1_g     = (const float*)d_in[3];
  const float* ln1_b     = (const float*)d_in[4];
  const float* lin_w     = (const float*)d_in[5];
  const float* lin_b     = (const float*)d_in[6];
  const float* inproj_w  = (const float*)d_in[7];
  const float* conv_w    = (const float*)d_in[8];
  const float* conv_b    = (const float*)d_in[9];
  const float* xproj_w   = (const float*)d_in[10];
  const float* dtproj_w  = (const float*)d_in[11];
  const float* dtproj_b  = (const float*)d_in[12];
  const float* A_logs    = (const float*)d_in[13];
  const float* Ds        = (const float*)d_in[14];
  const float* outnorm_g = (const float*)d_in[15];
  const float* outnorm_b = (const float*)d_in[16];
  const float* outproj_w = (const float*)d_in[17];

  // workspace layout (aliased where lifetimes allow)
  char* base = (char*)d_ws;
  float* xbuf = (float*)base;                        base += (size_t)BH * LL * CC * 4;   // 16.8 MB
  __hip_bfloat16* catn = (__hip_bfloat16*)base;      base += (size_t)BH * LL * 512 * 2;  // 16.8 MB (alias: yfin)
  __hip_bfloat16* xn = (__hip_bfloat16*)base;        base += (size_t)BH * LL * CC * 2;   // 8.4 MB
  char* xpre_region = base;                          base += (size_t)BH * LL * 512 * 2;  // 16.8 MB (xcpre bf16 | Dbl f32)
  __hip_bfloat16* zb = (__hip_bfloat16*)base;        base += (size_t)BH * LL * 512 * 2;  // 16.8 MB
  __hip_bfloat16* xcb = (__hip_bfloat16*)base;       base += (size_t)BH * LL * 512 * 2;  // 16.8 MB
  __hip_bfloat16* ysb = (__hip_bfloat16*)base;       base += (size_t)BH * 4 * LL * 512 * 2; // 67.1 MB
  // bf16 weight copies (converted each launch)
  __hip_bfloat16* lin_wb = (__hip_bfloat16*)base;    base += (size_t)2 * CC * 2 * CC * 2;      // 0.5 MB
  __hip_bfloat16* inproj_wb = (__hip_bfloat16*)base; base += (size_t)2 * 2 * DD * CC * 2;      // 1.0 MB
  __hip_bfloat16* xproj_wb = (__hip_bfloat16*)base;  base += (size_t)2 * 4 * 48 * DD * 2;      // 0.4 MB
  __hip_bfloat16* outproj_wb = (__hip_bfloat16*)base; base += (size_t)2 * CC * DD * 2;         // 0.5 MB
  // chunked-scan state
  float* hbuf = (float*)base;                        base += (size_t)NCH * 32768 * 16 * 4;     // 33.6 MB
  float* sdbuf = (float*)base;                       base += (size_t)NCH * 32768 * 4;          // 2.1 MB
  __hip_bfloat16* xcpre = (__hip_bfloat16*)xpre_region;
  float* Dbl = (float*)xpre_region;                  // written after xcpre is dead
  __hip_bfloat16* yfin = catn;                       // written after catn is dead

  const long n0 = (long)BH * LL * CC;
  const int M = BH * LL;

  // convert MFMA weights to bf16 (both layers at once)
  {
    long n;
    n = 2L * CC * 2 * CC;  k_cvtw<<<(int)((n + 255) / 256), 256, 0, stream>>>(lin_w, lin_wb, n);
    n = 2L * 2 * DD * CC;  k_cvtw<<<(int)((n + 255) / 256), 256, 0, stream>>>(inproj_w, inproj_wb, n);
    n = 2L * 4 * 48 * DD;  k_cvtw<<<(int)((n + 255) / 256), 256, 0, stream>>>(xproj_w, xproj_wb, n);
    n = 2L * CC * DD;      k_cvtw<<<(int)((n + 255) / 256), 256, 0, stream>>>(outproj_w, outproj_wb, n);
  }

  for (int i = 0; i < 2; i++) {
    const float* g1 = ln1_g + i * CC;
    const float* b1 = ln1_b + i * CC;
    if (i == 0) {
      k_ln_cat<<<M, 256, 0, stream>>>(xt, hx, g1, b1, catn);
      gemm_k<0><<<dim3(M / 64, 256 / 64), 64, 0, stream>>>(catn, lin_wb, 512, 256, lin_b, xn, nullptr, nullptr, nullptr);
    } else {
      k_ln<<<M, 256, 0, stream>>>(xbuf, g1, b1, xn);
    }
    // inproj: (M x 256) x (1024 x 256)^T -> xcpre | z
    gemm_k<1><<<dim3(M / 64, 1024 / 64), 64, 0, stream>>>(xn, inproj_wb + (size_t)i * 1024 * 256, 256, 1024,
                                                          nullptr, xcpre, zb, nullptr, nullptr);
    long nc = (long)BH * LL * DD;
    k_conv<<<(int)((nc + 255) / 256), 256, 0, stream>>>(xcpre, conv_w + (size_t)i * DD * 9, conv_b + i * DD, xcb);
    // xproj merged over 4 directions: N = 192, natural position order
    gemm_k<2><<<dim3(M / 64, 192 / 64), 64, 0, stream>>>(xcb, xproj_wb + (size_t)i * 4 * 48 * DD, 512, 192,
                                                         nullptr, nullptr, nullptr, Dbl, nullptr);
    // chunked scan
    const float* dtw_i = dtproj_w + (size_t)i * 4 * 512 * 16;
    const float* dtb_i = dtproj_b + (size_t)i * 4 * 512;
    const float* alog_i = A_logs + (size_t)i * 2048 * 16;
    const float* Ds_i = Ds + (size_t)i * 2048;
    k_scan1<<<dim3(8, 4, BH * NCH), 64, 0, stream>>>(Dbl, xcb, dtw_i, dtb_i, alog_i, hbuf, sdbuf);
    k_scan2a<<<524288 / 256, 256, 0, stream>>>(alog_i, sdbuf, hbuf);
    k_scan2b<<<dim3(8, 4, BH * NCH), 64, 0, stream>>>(Dbl, xcb, dtw_i, dtb_i, alog_i, Ds_i, hbuf, ysb);
    k_combine<<<M, 256, 0, stream>>>(ysb, zb, outnorm_g + i * DD, outnorm_b + i * DD, yfin);
    // outproj + residual (layer0: resid = xt input; layer1: in-place on xbuf)
    gemm_k<3><<<dim3(M / 64, 256 / 64), 64, 0, stream>>>(yfin, outproj_wb + (size_t)i * CC * DD, 512, 256,
                                                         nullptr, nullptr, nullptr, xbuf, (i == 0) ? xt : xbuf);
  }
  k_lstm<<<(int)((n0 + 255) / 256), 256, 0, stream>>>(xbuf, cx, (float*)d_out, n0);
}